// Round 14
// baseline (1580.164 us; speedup 1.0000x reference)
//
#include <hip/hip_runtime.h>
#include <hip/hip_bf16.h>

typedef __bf16 bf16_t;
typedef __bf16 bf16x8 __attribute__((ext_vector_type(8)));
typedef float  f32x4  __attribute__((ext_vector_type(4)));

#define DK 1024   // d_in  (K)
#define DN 1024   // d_out (N)
#define RNK 32
#define BM 128
#define BN 512
#define BK 32
#define NKT 32

// ---- Pass 1: W_eff = W + C @ V_r^T, bf16, PRE-SWIZZLED (R7 layout) ---------
__global__ void weff_kernel(const float* __restrict__ W,
                            const float* __restrict__ Vr,
                            const float* __restrict__ C,
                            bf16_t* __restrict__ WeffSw)
{
    const int o  = blockIdx.x;
    const int g  = threadIdx.x;
    const int d0 = g * 8;

    f32x4 cv[8];
#pragma unroll
    for (int q = 0; q < 8; ++q) cv[q] = *(const f32x4*)(C + o * RNK + q * 4);

    const f32x4* wrow = (const f32x4*)(W + (size_t)o * DK + d0);
    f32x4 w0 = wrow[0], w1 = wrow[1];
    float acc[8];
#pragma unroll
    for (int e = 0; e < 4; ++e) { acc[e] = w0[e]; acc[4 + e] = w1[e]; }

#pragma unroll
    for (int e = 0; e < 8; ++e) {
        const f32x4* vre = (const f32x4*)(Vr + (size_t)(d0 + e) * RNK);
        float s = 0.f;
#pragma unroll
        for (int q = 0; q < 8; ++q) {
            f32x4 v = vre[q];
            s += cv[q][0] * v[0] + cv[q][1] * v[1] + cv[q][2] * v[2] + cv[q][3] * v[3];
        }
        acc[e] += s;
    }

    bf16x8 out;
#pragma unroll
    for (int e = 0; e < 8; ++e) out[e] = (bf16_t)acc[e];

    const int bn = o >> 9, rloc = o & 511;
    const int kt = d0 >> 5, seg = (d0 >> 3) & 3;
    const int sw = seg ^ ((rloc >> 1) & 3);
    const size_t byte = (size_t)(bn * 32 + kt) * 32768 + rloc * 64 + (sw << 4);
    *(bf16x8*)((char*)WeffSw + byte) = out;
}

// ---- Pass 2: R13 GEMM verbatim (202 us anchor) -----------------------------
__global__ __launch_bounds__(512, 1) void corrlin_gemm_kernel(
    const float* __restrict__ X, const bf16_t* __restrict__ WeffSw,
    const float* __restrict__ bias, float* __restrict__ Out)
{
    __shared__ __align__(16) char smem[81920];
    char* Ab0 = smem;
    char* Ab1 = smem + 8192;
    char* Bb0 = smem + 16384;
    char* Bb1 = smem + 49152;

    const int tid = threadIdx.x;
    const int b0  = blockIdx.x;
    const int L  = (b0 & 7) * 128 + (b0 >> 3);
    const int bm = L >> 1;
    const int bn = L & 1;
    const int m0 = bm * BM;

    const int lane = tid & 63;
    const int wn   = tid >> 6;
    const int arow = tid >> 2;
    const int aseg = tid & 3;

    f32x4 acc[8][4] = {};
    f32x4 set0[2], set1[2];

    auto issueA = [&](int kt, f32x4* s) {
        const float* p = X + (size_t)(m0 + arow) * DK + kt * BK + aseg * 8;
        s[0] = *(const f32x4*)p;
        s[1] = *(const f32x4*)(p + 4);
    };
    auto storeA = [&](const f32x4* s, char* Ab) {
        const int sw = aseg ^ ((arow >> 1) & 3);
        bf16x8 v;
#pragma unroll
        for (int j = 0; j < 4; ++j) { v[j] = (bf16_t)s[0][j]; v[4 + j] = (bf16_t)s[1][j]; }
        *(bf16x8*)(Ab + arow * 64 + (sw << 4)) = v;
    };
    auto issueB = [&](int kt, char* Bb) {
        const char* g = (const char*)WeffSw + (size_t)(bn * 32 + kt) * 32768;
#pragma unroll
        for (int c = 0; c < 4; ++c) {
            const int lin = c * 8192 + wn * 1024;
            __builtin_amdgcn_global_load_lds(
                (const __attribute__((address_space(1))) void*)(g + lin + lane * 16),
                (__attribute__((address_space(3))) void*)(Bb + lin),
                16, 0, 0);
        }
    };
    auto readB = [&](const char* Bc, bf16x8* bfr) {
        const int kb = lane >> 4;
#pragma unroll
        for (int nf = 0; nf < 4; ++nf) {
            const int row = wn * 64 + nf * 16 + (lane & 15);
            bfr[nf] = *(const bf16x8*)(Bc + row * 64 + ((kb ^ ((row >> 1) & 3)) << 4));
        }
    };
    auto compute_h = [&](const char* Ac, int h, const bf16x8* bfr) {
        bf16x8 af[4];
        const int kb = lane >> 4;
#pragma unroll
        for (int i = 0; i < 4; ++i) {
            const int row = (h * 4 + i) * 16 + (lane & 15);
            af[i] = *(const bf16x8*)(Ac + row * 64 + ((kb ^ ((row >> 1) & 3)) << 4));
        }
        __builtin_amdgcn_s_setprio(1);
#pragma unroll
        for (int i = 0; i < 4; ++i)
#pragma unroll
            for (int nf = 0; nf < 4; ++nf)
                acc[h * 4 + i][nf] = __builtin_amdgcn_mfma_f32_16x16x32_bf16(
                    af[i], bfr[nf], acc[h * 4 + i][nf], 0, 0, 0);
        __builtin_amdgcn_s_setprio(0);
    };

    auto iter = [&](int t, const char* Ac, const char* Bc, char* An, char* Bn,
                    f32x4* aStore, f32x4* aFill) {
        if (t + 1 < NKT) issueB(t + 1, Bn);
        bf16x8 bfr[4];
        readB(Bc, bfr);
        compute_h(Ac, 0, bfr);
        if (t + 1 < NKT) storeA(aStore, An);
        if (t + 2 < NKT) issueA(t + 2, aFill);
        compute_h(Ac, 1, bfr);
        if (t + 2 < NKT) {
            asm volatile("s_waitcnt vmcnt(2) lgkmcnt(0)" ::: "memory");
            __builtin_amdgcn_s_barrier();
        } else if (t + 1 < NKT) {
            asm volatile("s_waitcnt vmcnt(0) lgkmcnt(0)" ::: "memory");
            __builtin_amdgcn_s_barrier();
        }
    };

    issueA(0, set0);
    issueB(0, Bb0);
    storeA(set0, Ab0);
    issueA(1, set1);
    asm volatile("s_waitcnt vmcnt(2) lgkmcnt(0)" ::: "memory");
    __builtin_amdgcn_s_barrier();

    for (int t = 0; t < NKT; t += 2) {
        iter(t,     Ab0, Bb0, Ab1, Bb1, set1, set0);
        iter(t + 1, Ab1, Bb1, Ab0, Bb0, set0, set1);
    }
    __syncthreads();

    float* tb = (float*)smem + wn * 1280;
    const int nbase = bn * BN + wn * 64;
    float bv[4];
#pragma unroll
    for (int nf = 0; nf < 4; ++nf) bv[nf] = bias[nbase + nf * 16 + (lane & 15)];

#pragma unroll
    for (int mf = 0; mf < 8; ++mf) {
#pragma unroll
        for (int nf = 0; nf < 4; ++nf)
#pragma unroll
            for (int j = 0; j < 4; ++j) {
                const int r = (lane >> 4) * 4 + j;
                const int c = nf * 16 + (lane & 15);
                tb[r * 80 + c] = acc[mf][nf][j] + bv[nf];
            }
        __syncthreads();
#pragma unroll
        for (int jj = 0; jj < 4; ++jj) {
            const int rr = jj * 4 + (lane >> 4);
            const int cc = (lane & 15) * 4;
            f32x4 v = *(const f32x4*)&tb[rr * 80 + cc];
            *(f32x4*)&Out[(size_t)(m0 + mf * 16 + rr) * DN + nbase + cc] = v;
        }
        __syncthreads();
    }
}

// ======================= ABLATION PROBES (REP=3 each) =======================
// Shared geometry with the real kernel: 81920B LDS (1 block/CU), 512 thr,
// nwg=1024. Core = readB + 2x compute_h + lgkmcnt(0) + barrier (76% util).

// Probe A: core + A-staging only (x loads, cvt, swizzled ds_write, dbuf).
__global__ __launch_bounds__(512, 1) void probe_A_stage(
    const float* __restrict__ X, float* ws)
{
    __shared__ __align__(16) char smem[81920];
    char* Ab0 = smem;
    char* Ab1 = smem + 8192;
    char* Bst = smem + 16384;      // static B source

    const int tid = threadIdx.x;
    const int b0  = blockIdx.x;
    const int L  = (b0 & 7) * 128 + (b0 >> 3);
    const int m0 = (L >> 1) * BM;
    const int lane = tid & 63;
    const int wn   = tid >> 6;
    const int arow = tid >> 2;
    const int aseg = tid & 3;

    for (int i = tid; i < 81920 / 16; i += 512)
        *(f32x4*)(smem + i * 16) = f32x4{0.f, 0.f, 0.f, 0.f};
    __syncthreads();

    f32x4 acc[8][4] = {};
    f32x4 set0[2], set1[2];

    auto issueA = [&](int kt, f32x4* s) {
        const float* p = X + (size_t)(m0 + arow) * DK + kt * BK + aseg * 8;
        s[0] = *(const f32x4*)p;
        s[1] = *(const f32x4*)(p + 4);
    };
    auto storeA = [&](const f32x4* s, char* Ab) {
        const int sw = aseg ^ ((arow >> 1) & 3);
        bf16x8 v;
#pragma unroll
        for (int j = 0; j < 4; ++j) { v[j] = (bf16_t)s[0][j]; v[4 + j] = (bf16_t)s[1][j]; }
        *(bf16x8*)(Ab + arow * 64 + (sw << 4)) = v;
    };
    auto readB = [&](const char* Bc, bf16x8* bfr) {
        const int kb = lane >> 4;
#pragma unroll
        for (int nf = 0; nf < 4; ++nf) {
            const int row = wn * 64 + nf * 16 + (lane & 15);
            bfr[nf] = *(const bf16x8*)(Bc + row * 64 + ((kb ^ ((row >> 1) & 3)) << 4));
        }
    };
    auto compute_h = [&](const char* Ac, int h, const bf16x8* bfr) {
        bf16x8 af[4];
        const int kb = lane >> 4;
#pragma unroll
        for (int i = 0; i < 4; ++i) {
            const int row = (h * 4 + i) * 16 + (lane & 15);
            af[i] = *(const bf16x8*)(Ac + row * 64 + ((kb ^ ((row >> 1) & 3)) << 4));
        }
        __builtin_amdgcn_s_setprio(1);
#pragma unroll
        for (int i = 0; i < 4; ++i)
#pragma unroll
            for (int nf = 0; nf < 4; ++nf)
                acc[h * 4 + i][nf] = __builtin_amdgcn_mfma_f32_16x16x32_bf16(
                    af[i], bfr[nf], acc[h * 4 + i][nf], 0, 0, 0);
        __builtin_amdgcn_s_setprio(0);
    };

    issueA(0, set0);
    issueA(1, set1);
    for (int rep = 0; rep < 3; ++rep)
    for (int t = 0; t < NKT; t += 2) {
        {   // even iter: compute Ab0, store set1->Ab1, refill set0
            bf16x8 bfr[4];
            readB(Bst, bfr);
            compute_h(Ab0, 0, bfr);
            storeA(set1, Ab1);
            issueA((t + 2) & 31, set0);
            compute_h(Ab0, 1, bfr);
            asm volatile("s_waitcnt lgkmcnt(0)" ::: "memory");
            __builtin_amdgcn_s_barrier();
        }
        {   // odd iter
            bf16x8 bfr[4];
            readB(Bst, bfr);
            compute_h(Ab1, 0, bfr);
            storeA(set0, Ab0);
            issueA((t + 3) & 31, set1);
            compute_h(Ab1, 1, bfr);
            asm volatile("s_waitcnt lgkmcnt(0)" ::: "memory");
            __builtin_amdgcn_s_barrier();
        }
    }
    asm volatile("s_waitcnt vmcnt(0)" ::: "memory");
    float s = 0.f;
#pragma unroll
    for (int mf = 0; mf < 8; ++mf)
#pragma unroll
        for (int nf = 0; nf < 4; ++nf)
#pragma unroll
            for (int j = 0; j < 4; ++j) s += acc[mf][nf][j];
    asm volatile("" :: "v"(s));
    if (tid == 0) ws[blockIdx.x] = s;
}

// Probe B: core + B-DMA only (4x gload_lds/wave/iter, dbuf, vmcnt(0) drain).
__global__ __launch_bounds__(512, 1) void probe_B_dma(
    const bf16_t* __restrict__ WeffSw, float* ws)
{
    __shared__ __align__(16) char smem[81920];
    char* Ast = smem;              // static A source
    char* Bb0 = smem + 16384;
    char* Bb1 = smem + 49152;

    const int tid = threadIdx.x;
    const int b0  = blockIdx.x;
    const int L  = (b0 & 7) * 128 + (b0 >> 3);
    const int bn = L & 1;
    const int lane = tid & 63;
    const int wn   = tid >> 6;

    for (int i = tid; i < 81920 / 16; i += 512)
        *(f32x4*)(smem + i * 16) = f32x4{0.f, 0.f, 0.f, 0.f};
    __syncthreads();

    f32x4 acc[8][4] = {};

    auto issueB = [&](int kt, char* Bb) {
        const char* g = (const char*)WeffSw + (size_t)(bn * 32 + kt) * 32768;
#pragma unroll
        for (int c = 0; c < 4; ++c) {
            const int lin = c * 8192 + wn * 1024;
            __builtin_amdgcn_global_load_lds(
                (const __attribute__((address_space(1))) void*)(g + lin + lane * 16),
                (__attribute__((address_space(3))) void*)(Bb + lin),
                16, 0, 0);
        }
    };
    auto readB = [&](const char* Bc, bf16x8* bfr) {
        const int kb = lane >> 4;
#pragma unroll
        for (int nf = 0; nf < 4; ++nf) {
            const int row = wn * 64 + nf * 16 + (lane & 15);
            bfr[nf] = *(const bf16x8*)(Bc + row * 64 + ((kb ^ ((row >> 1) & 3)) << 4));
        }
    };
    auto compute_h = [&](const char* Ac, int h, const bf16x8* bfr) {
        bf16x8 af[4];
        const int kb = lane >> 4;
#pragma unroll
        for (int i = 0; i < 4; ++i) {
            const int row = (h * 4 + i) * 16 + (lane & 15);
            af[i] = *(const bf16x8*)(Ac + row * 64 + ((kb ^ ((row >> 1) & 3)) << 4));
        }
        __builtin_amdgcn_s_setprio(1);
#pragma unroll
        for (int i = 0; i < 4; ++i)
#pragma unroll
            for (int nf = 0; nf < 4; ++nf)
                acc[h * 4 + i][nf] = __builtin_amdgcn_mfma_f32_16x16x32_bf16(
                    af[i], bfr[nf], acc[h * 4 + i][nf], 0, 0, 0);
        __builtin_amdgcn_s_setprio(0);
    };

    issueB(0, Bb0);
    asm volatile("s_waitcnt vmcnt(0)" ::: "memory");
    __builtin_amdgcn_s_barrier();
    for (int rep = 0; rep < 3; ++rep)
    for (int t = 0; t < NKT; t += 2) {
        {
            issueB((t + 1) & 31, Bb1);
            bf16x8 bfr[4];
            readB(Bb0, bfr);
            compute_h(Ast, 0, bfr);
            compute_h(Ast, 1, bfr);
            asm volatile("s_waitcnt vmcnt(0) lgkmcnt(0)" ::: "memory");
            __builtin_amdgcn_s_barrier();
        }
        {
            issueB((t + 2) & 31, Bb0);
            bf16x8 bfr[4];
            readB(Bb1, bfr);
            compute_h(Ast, 0, bfr);
            compute_h(Ast, 1, bfr);
            asm volatile("s_waitcnt vmcnt(0) lgkmcnt(0)" ::: "memory");
            __builtin_amdgcn_s_barrier();
        }
    }
    float s = 0.f;
#pragma unroll
    for (int mf = 0; mf < 8; ++mf)
#pragma unroll
        for (int nf = 0; nf < 4; ++nf)
#pragma unroll
            for (int j = 0; j < 4; ++j) s += acc[mf][nf][j];
    asm volatile("" :: "v"(s));
    if (tid == 0) ws[blockIdx.x] = s;
}

// Probe B2: same B traffic, reg-staged (global->VGPR->ds_write, T14 split).
__global__ __launch_bounds__(512, 1) void probe_B_reg(
    const bf16_t* __restrict__ WeffSw, float* ws)
{
    __shared__ __align__(16) char smem[81920];
    char* Ast = smem;
    char* Bb0 = smem + 16384;
    char* Bb1 = smem + 49152;

    const int tid = threadIdx.x;
    const int b0  = blockIdx.x;
    const int L  = (b0 & 7) * 128 + (b0 >> 3);
    const int bn = L & 1;
    const int lane = tid & 63;
    const int wn   = tid >> 6;

    for (int i = tid; i < 81920 / 16; i += 512)
        *(f32x4*)(smem + i * 16) = f32x4{0.f, 0.f, 0.f, 0.f};
    __syncthreads();

    f32x4 acc[8][4] = {};
    uint4 breg[4];

    auto loadBreg = [&](int kt) {
        const char* g = (const char*)WeffSw + (size_t)(bn * 32 + kt) * 32768;
#pragma unroll
        for (int c = 0; c < 4; ++c)
            breg[c] = *(const uint4*)(g + c * 8192 + wn * 1024 + lane * 16);
    };
    auto writeBreg = [&](char* Bb) {
#pragma unroll
        for (int c = 0; c < 4; ++c)
            *(uint4*)(Bb + c * 8192 + wn * 1024 + lane * 16) = breg[c];
    };
    auto readB = [&](const char* Bc, bf16x8* bfr) {
        const int kb = lane >> 4;
#pragma unroll
        for (int nf = 0; nf < 4; ++nf) {
            const int row = wn * 64 + nf * 16 + (lane & 15);
            bfr[nf] = *(const bf16x8*)(Bc + row * 64 + ((kb ^ ((row >> 1) & 3)) << 4));
        }
    };
    auto compute_h = [&](const char* Ac, int h, const bf16x8* bfr) {
        bf16x8 af[4];
        const int kb = lane >> 4;
#pragma unroll
        for (int i = 0; i < 4; ++i) {
            const int row = (h * 4 + i) * 16 + (lane & 15);
            af[i] = *(const bf16x8*)(Ac + row * 64 + ((kb ^ ((row >> 1) & 3)) << 4));
        }
        __builtin_amdgcn_s_setprio(1);
#pragma unroll
        for (int i = 0; i < 4; ++i)
#pragma unroll
            for (int nf = 0; nf < 4; ++nf)
                acc[h * 4 + i][nf] = __builtin_amdgcn_mfma_f32_16x16x32_bf16(
                    af[i], bfr[nf], acc[h * 4 + i][nf], 0, 0, 0);
        __builtin_amdgcn_s_setprio(0);
    };

    loadBreg(0);
    writeBreg(Bb0);
    asm volatile("s_waitcnt lgkmcnt(0)" ::: "memory");
    __builtin_amdgcn_s_barrier();
    for (int rep = 0; rep < 3; ++rep)
    for (int t = 0; t < NKT; t += 2) {
        {
            loadBreg((t + 1) & 31);          // issue early (T14)
            bf16x8 bfr[4];
            readB(Bb0, bfr);
            compute_h(Ast, 0, bfr);
            writeBreg(Bb1);                  // auto-waits loads; hides under h0
            compute_h(Ast, 1, bfr);
            asm volatile("s_waitcnt lgkmcnt(0)" ::: "memory");
            __builtin_amdgcn_s_barrier();
        }
        {
            loadBreg((t + 2) & 31);
            bf16x8 bfr[4];
            readB(Bb1, bfr);
            compute_h(Ast, 0, bfr);
            writeBreg(Bb0);
            compute_h(Ast, 1, bfr);
            asm volatile("s_waitcnt lgkmcnt(0)" ::: "memory");
            __builtin_amdgcn_s_barrier();
        }
    }
    float s = 0.f;
#pragma unroll
    for (int mf = 0; mf < 8; ++mf)
#pragma unroll
        for (int nf = 0; nf < 4; ++nf)
#pragma unroll
            for (int j = 0; j < 4; ++j) s += acc[mf][nf][j];
    asm volatile("" :: "v"(s));
    if (tid == 0) ws[blockIdx.x] = s;
}

extern "C" void kernel_launch(void* const* d_in, const int* in_sizes, int n_in,
                              void* d_out, int out_size, void* d_ws, size_t ws_size,
                              hipStream_t stream) {
    const float* x  = (const float*)d_in[0];
    const float* W  = (const float*)d_in[1];
    const float* b  = (const float*)d_in[2];
    const float* Vr = (const float*)d_in[3];
    const float* C  = (const float*)d_in[4];
    float* out = (float*)d_out;

    const int M = in_sizes[0] / DK;            // 65536
    bf16_t* WeffSw = (bf16_t*)d_ws;            // 2 MB pre-swizzled W_eff
    float* wsp = (float*)((char*)d_ws + (2u << 20));

    weff_kernel<<<DN, 128, 0, stream>>>(W, Vr, C, WeffSw);

    const int mtiles = M / BM;                 // 512
    const int nwg = mtiles * (DN / BN);        // 1024
    corrlin_gemm_kernel<<<nwg, 512, 0, stream>>>(x, WeffSw, b, out);

    probe_A_stage<<<nwg, 512, 0, stream>>>(x, wsp);
    probe_B_dma  <<<nwg, 512, 0, stream>>>(WeffSw, wsp + 1024);
    probe_B_reg  <<<nwg, 512, 0, stream>>>(WeffSw, wsp + 2048);
}

// Round 15
// 295.750 us; speedup vs baseline: 5.3429x; 5.3429x over previous
//
#include <hip/hip_runtime.h>
#include <hip/hip_bf16.h>

typedef __bf16 bf16_t;
typedef __bf16 bf16x8 __attribute__((ext_vector_type(8)));
typedef float  f32x4  __attribute__((ext_vector_type(4)));

#define DK 1024   // d_in  (K)
#define DN 1024   // d_out (N)
#define RNK 32
#define BM 128
#define BN 512
#define BK 32
#define NKT 32

// ---- Pass 1: W_eff = W + C @ V_r^T, bf16, PRE-SWIZZLED (R7 layout) ---------
__global__ void weff_kernel(const float* __restrict__ W,
                            const float* __restrict__ Vr,
                            const float* __restrict__ C,
                            bf16_t* __restrict__ WeffSw)
{
    const int o  = blockIdx.x;
    const int g  = threadIdx.x;
    const int d0 = g * 8;

    f32x4 cv[8];
#pragma unroll
    for (int q = 0; q < 8; ++q) cv[q] = *(const f32x4*)(C + o * RNK + q * 4);

    const f32x4* wrow = (const f32x4*)(W + (size_t)o * DK + d0);
    f32x4 w0 = wrow[0], w1 = wrow[1];
    float acc[8];
#pragma unroll
    for (int e = 0; e < 4; ++e) { acc[e] = w0[e]; acc[4 + e] = w1[e]; }

#pragma unroll
    for (int e = 0; e < 8; ++e) {
        const f32x4* vre = (const f32x4*)(Vr + (size_t)(d0 + e) * RNK);
        float s = 0.f;
#pragma unroll
        for (int q = 0; q < 8; ++q) {
            f32x4 v = vre[q];
            s += cv[q][0] * v[0] + cv[q][1] * v[1] + cv[q][2] * v[2] + cv[q][3] * v[3];
        }
        acc[e] += s;
    }

    bf16x8 out;
#pragma unroll
    for (int e = 0; e < 8; ++e) out[e] = (bf16_t)acc[e];

    const int bn = o >> 9, rloc = o & 511;
    const int kt = d0 >> 5, seg = (d0 >> 3) & 3;
    const int sw = seg ^ ((rloc >> 1) & 3);
    const size_t byte = (size_t)(bn * 32 + kt) * 32768 + rloc * 64 + (sw << 4);
    *(bf16x8*)((char*)WeffSw + byte) = out;
}

// ---- Pass 1b: x fp32 -> bf16, PRE-SWIZZLED chunks [bm(512)][kt(32)] of 8KB -
// Same swizzled LDS image as the old storeA produced: within chunk,
// byte(rloc,seg) = rloc*64 + ((seg ^ ((rloc>>1)&3))<<4). Reads perfectly
// coalesced (thread g reads 32B at g*32); writes in 64B granules.
__global__ void xconv_kernel(const float* __restrict__ X, bf16_t* __restrict__ Xsw)
{
    const int g = blockIdx.x * 256 + threadIdx.x;   // 0 .. 65536*128-1
    const int row  = g >> 7;
    const int sidx = g & 127;        // 8-float segment within the row

    const float* p = X + (size_t)row * DK + sidx * 8;
    f32x4 a = *(const f32x4*)p;
    f32x4 b = *(const f32x4*)(p + 4);
    bf16x8 v;
#pragma unroll
    for (int e = 0; e < 4; ++e) { v[e] = (bf16_t)a[e]; v[4 + e] = (bf16_t)b[e]; }

    const int bm = row >> 7, rloc = row & 127;
    const int kt = sidx >> 2, seg = sidx & 3;
    const int sw = seg ^ ((rloc >> 1) & 3);
    const size_t byte = (size_t)(bm * 32 + kt) * 8192 + rloc * 64 + (sw << 4);
    *(bf16x8*)((char*)Xsw + byte) = v;
}

// ---- Pass 2 (primary): all-DMA GEMM. 128x512 tile, BK=32, 8 waves ----------
// A and B both staged by global_load_lds from pre-swizzled images: no reg
// staging, no cvt, no ds_write -- homogeneous staging (probe_B_dma pattern,
// 74us at 76% core util). LDS 80KB -> 2 blocks/CU (4 waves/SIMD).
__global__ __launch_bounds__(512, 2) void corrlin_gemm_dma(
    const bf16_t* __restrict__ Xsw, const bf16_t* __restrict__ WeffSw,
    const float* __restrict__ bias, float* __restrict__ Out)
{
    __shared__ __align__(16) char smem[81920];
    char* Ab0 = smem;                // 8KB each
    char* Ab1 = smem + 8192;
    char* Bb0 = smem + 16384;        // 32KB each
    char* Bb1 = smem + 49152;

    const int tid = threadIdx.x;
    const int b0  = blockIdx.x;
    const int L  = (b0 & 7) * 128 + (b0 >> 3);   // XCD-bijective, nwg=1024
    const int bm = L >> 1;
    const int bn = L & 1;

    const int lane = tid & 63;
    const int wn   = tid >> 6;

    f32x4 acc[8][4] = {};

    auto issueA = [&](int kt, char* Ab) {
        const char* g = (const char*)Xsw + (size_t)(bm * 32 + kt) * 8192;
        __builtin_amdgcn_global_load_lds(
            (const __attribute__((address_space(1))) void*)(g + wn * 1024 + lane * 16),
            (__attribute__((address_space(3))) void*)(Ab + wn * 1024),
            16, 0, 0);
    };
    auto issueB = [&](int kt, char* Bb) {
        const char* g = (const char*)WeffSw + (size_t)(bn * 32 + kt) * 32768;
#pragma unroll
        for (int c = 0; c < 4; ++c) {
            const int lin = c * 8192 + wn * 1024;
            __builtin_amdgcn_global_load_lds(
                (const __attribute__((address_space(1))) void*)(g + lin + lane * 16),
                (__attribute__((address_space(3))) void*)(Bb + lin),
                16, 0, 0);
        }
    };
    auto readB = [&](const char* Bc, bf16x8* bfr) {
        const int kb = lane >> 4;
#pragma unroll
        for (int nf = 0; nf < 4; ++nf) {
            const int row = wn * 64 + nf * 16 + (lane & 15);
            bfr[nf] = *(const bf16x8*)(Bc + row * 64 + ((kb ^ ((row >> 1) & 3)) << 4));
        }
    };
    auto compute_h = [&](const char* Ac, int h, const bf16x8* bfr) {
        bf16x8 af[4];
        const int kb = lane >> 4;
#pragma unroll
        for (int i = 0; i < 4; ++i) {
            const int row = (h * 4 + i) * 16 + (lane & 15);
            af[i] = *(const bf16x8*)(Ac + row * 64 + ((kb ^ ((row >> 1) & 3)) << 4));
        }
        __builtin_amdgcn_s_setprio(1);
#pragma unroll
        for (int i = 0; i < 4; ++i)
#pragma unroll
            for (int nf = 0; nf < 4; ++nf)
                acc[h * 4 + i][nf] = __builtin_amdgcn_mfma_f32_16x16x32_bf16(
                    af[i], bfr[nf], acc[h * 4 + i][nf], 0, 0, 0);
        __builtin_amdgcn_s_setprio(0);
    };

    // prologue: tile 0 DMA, drain, go
    issueB(0, Bb0);
    issueA(0, Ab0);
    asm volatile("s_waitcnt vmcnt(0)" ::: "memory");
    __builtin_amdgcn_s_barrier();

    for (int t = 0; t < NKT; ++t) {
        const char* Ac = (t & 1) ? Ab1 : Ab0;
        const char* Bc = (t & 1) ? Bb1 : Bb0;
        char* An = (t & 1) ? Ab0 : Ab1;
        char* Bn = (t & 1) ? Bb0 : Bb1;
        if (t + 1 < NKT) { issueB(t + 1, Bn); issueA(t + 1, An); }
        bf16x8 bfr[4];
        readB(Bc, bfr);
        compute_h(Ac, 0, bfr);
        compute_h(Ac, 1, bfr);
        asm volatile("s_waitcnt vmcnt(0) lgkmcnt(0)" ::: "memory");
        __builtin_amdgcn_s_barrier();
    }
    __syncthreads();

    // epilogue: per-wave LDS transpose -> full-line f32x4 stores
    float* tb = (float*)smem + wn * 1280;
    const int nbase = bn * BN + wn * 64;
    const int m0 = bm * BM;
    float bv[4];
#pragma unroll
    for (int nf = 0; nf < 4; ++nf) bv[nf] = bias[nbase + nf * 16 + (lane & 15)];

#pragma unroll
    for (int mf = 0; mf < 8; ++mf) {
#pragma unroll
        for (int nf = 0; nf < 4; ++nf)
#pragma unroll
            for (int j = 0; j < 4; ++j) {
                const int r = (lane >> 4) * 4 + j;
                const int c = nf * 16 + (lane & 15);
                tb[r * 80 + c] = acc[mf][nf][j] + bv[nf];
            }
        __syncthreads();
#pragma unroll
        for (int jj = 0; jj < 4; ++jj) {
            const int rr = jj * 4 + (lane >> 4);
            const int cc = (lane & 15) * 4;
            f32x4 v = *(const f32x4*)&tb[rr * 80 + cc];
            *(f32x4*)&Out[(size_t)(m0 + mf * 16 + rr) * DN + nbase + cc] = v;
        }
        __syncthreads();
    }
}

// ---- Pass 2 (fallback, ws too small): R13 GEMM verbatim --------------------
__global__ __launch_bounds__(512, 1) void corrlin_gemm_fb(
    const float* __restrict__ X, const bf16_t* __restrict__ WeffSw,
    const float* __restrict__ bias, float* __restrict__ Out)
{
    __shared__ __align__(16) char smem[81920];
    char* Ab0 = smem;
    char* Ab1 = smem + 8192;
    char* Bb0 = smem + 16384;
    char* Bb1 = smem + 49152;

    const int tid = threadIdx.x;
    const int b0  = blockIdx.x;
    const int L  = (b0 & 7) * 128 + (b0 >> 3);
    const int bm = L >> 1;
    const int bn = L & 1;
    const int m0 = bm * BM;

    const int lane = tid & 63;
    const int wn   = tid >> 6;
    const int arow = tid >> 2;
    const int aseg = tid & 3;

    f32x4 acc[8][4] = {};
    f32x4 set0[2], set1[2];

    auto issueA = [&](int kt, f32x4* s) {
        const float* p = X + (size_t)(m0 + arow) * DK + kt * BK + aseg * 8;
        s[0] = *(const f32x4*)p;
        s[1] = *(const f32x4*)(p + 4);
    };
    auto storeA = [&](const f32x4* s, char* Ab) {
        const int sw = aseg ^ ((arow >> 1) & 3);
        bf16x8 v;
#pragma unroll
        for (int j = 0; j < 4; ++j) { v[j] = (bf16_t)s[0][j]; v[4 + j] = (bf16_t)s[1][j]; }
        *(bf16x8*)(Ab + arow * 64 + (sw << 4)) = v;
    };
    auto issueB = [&](int kt, char* Bb) {
        const char* g = (const char*)WeffSw + (size_t)(bn * 32 + kt) * 32768;
#pragma unroll
        for (int c = 0; c < 4; ++c) {
            const int lin = c * 8192 + wn * 1024;
            __builtin_amdgcn_global_load_lds(
                (const __attribute__((address_space(1))) void*)(g + lin + lane * 16),
                (__attribute__((address_space(3))) void*)(Bb + lin),
                16, 0, 0);
        }
    };
    auto readB = [&](const char* Bc, bf16x8* bfr) {
        const int kb = lane >> 4;
#pragma unroll
        for (int nf = 0; nf < 4; ++nf) {
            const int row = wn * 64 + nf * 16 + (lane & 15);
            bfr[nf] = *(const bf16x8*)(Bc + row * 64 + ((kb ^ ((row >> 1) & 3)) << 4));
        }
    };
    auto compute_h = [&](const char* Ac, int h, const bf16x8* bfr) {
        bf16x8 af[4];
        const int kb = lane >> 4;
#pragma unroll
        for (int i = 0; i < 4; ++i) {
            const int row = (h * 4 + i) * 16 + (lane & 15);
            af[i] = *(const bf16x8*)(Ac + row * 64 + ((kb ^ ((row >> 1) & 3)) << 4));
        }
        __builtin_amdgcn_s_setprio(1);
#pragma unroll
        for (int i = 0; i < 4; ++i)
#pragma unroll
            for (int nf = 0; nf < 4; ++nf)
                acc[h * 4 + i][nf] = __builtin_amdgcn_mfma_f32_16x16x32_bf16(
                    af[i], bfr[nf], acc[h * 4 + i][nf], 0, 0, 0);
        __builtin_amdgcn_s_setprio(0);
    };

    auto iter = [&](int t, const char* Ac, const char* Bc, char* An, char* Bn,
                    f32x4* aStore, f32x4* aFill) {
        if (t + 1 < NKT) issueB(t + 1, Bn);
        bf16x8 bfr[4];
        readB(Bc, bfr);
        compute_h(Ac, 0, bfr);
        if (t + 1 < NKT) storeA(aStore, An);
        if (t + 2 < NKT) issueA(t + 2, aFill);
        compute_h(Ac, 1, bfr);
        if (t + 2 < NKT) {
            asm volatile("s_waitcnt vmcnt(2) lgkmcnt(0)" ::: "memory");
            __builtin_amdgcn_s_barrier();
        } else if (t + 1 < NKT) {
            asm volatile("s_waitcnt vmcnt(0) lgkmcnt(0)" ::: "memory");
            __builtin_amdgcn_s_barrier();
        }
    };

    issueA(0, set0);
    issueB(0, Bb0);
    storeA(set0, Ab0);
    issueA(1, set1);
    asm volatile("s_waitcnt vmcnt(2) lgkmcnt(0)" ::: "memory");
    __builtin_amdgcn_s_barrier();

    for (int t = 0; t < NKT; t += 2) {
        iter(t,     Ab0, Bb0, Ab1, Bb1, set1, set0);
        iter(t + 1, Ab1, Bb1, Ab0, Bb0, set0, set1);
    }
    __syncthreads();

    float* tb = (float*)smem + wn * 1280;
    const int nbase = bn * BN + wn * 64;
    float bv[4];
#pragma unroll
    for (int nf = 0; nf < 4; ++nf) bv[nf] = bias[nbase + nf * 16 + (lane & 15)];

#pragma unroll
    for (int mf = 0; mf < 8; ++mf) {
#pragma unroll
        for (int nf = 0; nf < 4; ++nf)
#pragma unroll
            for (int j = 0; j < 4; ++j) {
                const int r = (lane >> 4) * 4 + j;
                const int c = nf * 16 + (lane & 15);
                tb[r * 80 + c] = acc[mf][nf][j] + bv[nf];
            }
        __syncthreads();
#pragma unroll
        for (int jj = 0; jj < 4; ++jj) {
            const int rr = jj * 4 + (lane >> 4);
            const int cc = (lane & 15) * 4;
            f32x4 v = *(const f32x4*)&tb[rr * 80 + cc];
            *(f32x4*)&Out[(size_t)(m0 + mf * 16 + rr) * DN + nbase + cc] = v;
        }
        __syncthreads();
    }
}

extern "C" void kernel_launch(void* const* d_in, const int* in_sizes, int n_in,
                              void* d_out, int out_size, void* d_ws, size_t ws_size,
                              hipStream_t stream) {
    const float* x  = (const float*)d_in[0];
    const float* W  = (const float*)d_in[1];
    const float* b  = (const float*)d_in[2];
    const float* Vr = (const float*)d_in[3];
    const float* C  = (const float*)d_in[4];
    float* out = (float*)d_out;

    const int M = in_sizes[0] / DK;            // 65536
    bf16_t* WeffSw = (bf16_t*)d_ws;            // 2 MB pre-swizzled W_eff
    bf16_t* Xsw = (bf16_t*)((char*)d_ws + (2u << 20));  // 128 MB pre-swizzled x

    const size_t need = (2u << 20) + (size_t)M * DK * sizeof(bf16_t);

    weff_kernel<<<DN, 128, 0, stream>>>(W, Vr, C, WeffSw);

    const int mtiles = M / BM;                 // 512
    const int nwg = mtiles * (DN / BN);        // 1024

    if (ws_size >= need) {
        xconv_kernel<<<(M * (DK / 8)) / 256, 256, 0, stream>>>(x, Xsw);
        corrlin_gemm_dma<<<nwg, 512, 0, stream>>>(Xsw, WeffSw, b, out);
    } else {
        corrlin_gemm_fb<<<nwg, 512, 0, stream>>>(x, WeffSw, b, out);
    }
}

// Round 16
// 263.662 us; speedup vs baseline: 5.9932x; 1.1217x over previous
//
#include <hip/hip_runtime.h>
#include <hip/hip_bf16.h>

typedef __bf16 bf16_t;
typedef __bf16 bf16x8 __attribute__((ext_vector_type(8)));
typedef float  f32x4  __attribute__((ext_vector_type(4)));

#define DK 1024   // d_in  (K)
#define DN 1024   // d_out (N)
#define RNK 32
#define BM 128
#define BN 512
#define BK 32
#define NKT 32

// ---- Pass 1: W_eff = W + C @ V_r^T, bf16, PRE-SWIZZLED (R7 layout) ---------
__global__ void weff_kernel(const float* __restrict__ W,
                            const float* __restrict__ Vr,
                            const float* __restrict__ C,
                            bf16_t* __restrict__ WeffSw)
{
    const int o  = blockIdx.x;
    const int g  = threadIdx.x;
    const int d0 = g * 8;

    f32x4 cv[8];
#pragma unroll
    for (int q = 0; q < 8; ++q) cv[q] = *(const f32x4*)(C + o * RNK + q * 4);

    const f32x4* wrow = (const f32x4*)(W + (size_t)o * DK + d0);
    f32x4 w0 = wrow[0], w1 = wrow[1];
    float acc[8];
#pragma unroll
    for (int e = 0; e < 4; ++e) { acc[e] = w0[e]; acc[4 + e] = w1[e]; }

#pragma unroll
    for (int e = 0; e < 8; ++e) {
        const f32x4* vre = (const f32x4*)(Vr + (size_t)(d0 + e) * RNK);
        float s = 0.f;
#pragma unroll
        for (int q = 0; q < 8; ++q) {
            f32x4 v = vre[q];
            s += cv[q][0] * v[0] + cv[q][1] * v[1] + cv[q][2] * v[2] + cv[q][3] * v[3];
        }
        acc[e] += s;
    }

    bf16x8 out;
#pragma unroll
    for (int e = 0; e < 8; ++e) out[e] = (bf16_t)acc[e];

    const int bn = o >> 9, rloc = o & 511;
    const int kt = d0 >> 5, seg = (d0 >> 3) & 3;
    const int sw = seg ^ ((rloc >> 1) & 3);
    const size_t byte = (size_t)(bn * 32 + kt) * 32768 + rloc * 64 + (sw << 4);
    *(bf16x8*)((char*)WeffSw + byte) = out;
}

// ---- Pass 1b: x fp32 -> bf16 pre-swizzled, WRITE-COALESCED mapping ---------
// Thread handles one 16B granule addressed chunk-major: consecutive threads
// write consecutive 16B (perfectly sequential 4KB/block); reads come in 128B
// runs. Image identical to R15 (verified passing): within chunk c=bm*32+kt,
// byte(rloc,seg) = rloc*64 + ((seg ^ ((rloc>>1)&3))<<4), data = x[row][kt*32+seg*8..+8).
__global__ void xconv_kernel(const float* __restrict__ X, bf16_t* __restrict__ Xsw)
{
    const int g = blockIdx.x * 256 + threadIdx.x;
    const int c      = g >> 9;          // chunk index (bm*32 + kt)
    const int within = g & 511;
    const int rloc = within >> 2;
    const int seg  = within & 3;
    const int bm = c >> 5, kt = c & 31;

    const int row = bm * 128 + rloc;
    const float* p = X + (size_t)row * DK + kt * 32 + seg * 8;
    f32x4 a = *(const f32x4*)p;
    f32x4 b = *(const f32x4*)(p + 4);
    bf16x8 v;
#pragma unroll
    for (int e = 0; e < 4; ++e) { v[e] = (bf16_t)a[e]; v[4 + e] = (bf16_t)b[e]; }

    const int sw = seg ^ ((rloc >> 1) & 3);
    const size_t byte = (size_t)c * 8192 + rloc * 64 + (sw << 4);
    *(bf16x8*)((char*)Xsw + byte) = v;
}

// ---- Pass 2: all-DMA GEMM, uniform depth-2, counted vmcnt(5) ---------------
// Triple-buffered A(3x8K)+B(3x32K)=120KB. Iter t: issue tile t+2 (5 gload_lds),
// compute tile t, vmcnt(5) drains tile t+1 (issued a full iter ago), barrier.
// Never vmcnt(0) in steady state. Probe-validated core (76% util regime).
__global__ __launch_bounds__(512, 1) void corrlin_gemm_dma(
    const bf16_t* __restrict__ Xsw, const bf16_t* __restrict__ WeffSw,
    const float* __restrict__ bias, float* __restrict__ Out)
{
    __shared__ __align__(16) char smem[122880];
    char* Aq0 = smem;                 // 8KB each
    char* Aq1 = smem + 8192;
    char* Aq2 = smem + 16384;
    char* Bq0 = smem + 24576;         // 32KB each
    char* Bq1 = smem + 57344;
    char* Bq2 = smem + 90112;

    const int tid = threadIdx.x;
    const int b0  = blockIdx.x;
    const int L  = (b0 & 7) * 128 + (b0 >> 3);   // XCD-bijective, nwg=1024
    const int bm = L >> 1;
    const int bn = L & 1;

    const int lane = tid & 63;
    const int wn   = tid >> 6;

    f32x4 acc[8][4] = {};

    auto issueA = [&](int kt, char* Ab) {
        const char* g = (const char*)Xsw + (size_t)(bm * 32 + kt) * 8192;
        __builtin_amdgcn_global_load_lds(
            (const __attribute__((address_space(1))) void*)(g + wn * 1024 + lane * 16),
            (__attribute__((address_space(3))) void*)(Ab + wn * 1024),
            16, 0, 0);
    };
    auto issueB = [&](int kt, char* Bb) {
        const char* g = (const char*)WeffSw + (size_t)(bn * 32 + kt) * 32768;
#pragma unroll
        for (int c = 0; c < 4; ++c) {
            const int lin = c * 8192 + wn * 1024;
            __builtin_amdgcn_global_load_lds(
                (const __attribute__((address_space(1))) void*)(g + lin + lane * 16),
                (__attribute__((address_space(3))) void*)(Bb + lin),
                16, 0, 0);
        }
    };
    auto readB = [&](const char* Bc, bf16x8* bfr) {
        const int kb = lane >> 4;
#pragma unroll
        for (int nf = 0; nf < 4; ++nf) {
            const int row = wn * 64 + nf * 16 + (lane & 15);
            bfr[nf] = *(const bf16x8*)(Bc + row * 64 + ((kb ^ ((row >> 1) & 3)) << 4));
        }
    };
    auto compute_h = [&](const char* Ac, int h, const bf16x8* bfr) {
        bf16x8 af[4];
        const int kb = lane >> 4;
#pragma unroll
        for (int i = 0; i < 4; ++i) {
            const int row = (h * 4 + i) * 16 + (lane & 15);
            af[i] = *(const bf16x8*)(Ac + row * 64 + ((kb ^ ((row >> 1) & 3)) << 4));
        }
        __builtin_amdgcn_s_setprio(1);
#pragma unroll
        for (int i = 0; i < 4; ++i)
#pragma unroll
            for (int nf = 0; nf < 4; ++nf)
                acc[h * 4 + i][nf] = __builtin_amdgcn_mfma_f32_16x16x32_bf16(
                    af[i], bfr[nf], acc[h * 4 + i][nf], 0, 0, 0);
        __builtin_amdgcn_s_setprio(0);
    };

    // steady-state iteration: t+2 <= 31 guaranteed by caller
    auto iterM = [&](int t, const char* Ac, const char* Bc, char* An2, char* Bn2) {
        issueB(t + 2, Bn2);
        issueA(t + 2, An2);
        bf16x8 bfr[4];
        readB(Bc, bfr);
        compute_h(Ac, 0, bfr);
        compute_h(Ac, 1, bfr);
        asm volatile("s_waitcnt vmcnt(5) lgkmcnt(0)" ::: "memory");  // drain tile t+1
        __builtin_amdgcn_s_barrier();
    };

    // ---- prologue: tiles 0,1 issued; tile 0 landed (vmcnt(5)) --------------
    issueB(0, Bq0); issueA(0, Aq0);
    issueB(1, Bq1); issueA(1, Aq1);
    asm volatile("s_waitcnt vmcnt(5)" ::: "memory");    // tile 0 complete
    __builtin_amdgcn_s_barrier();

    // main: t = 0..29, 3-cyclic buffers, guard-free
    for (int t = 0; t < 30; t += 3) {
        iterM(t,     Aq0, Bq0, Aq2, Bq2);
        iterM(t + 1, Aq1, Bq1, Aq0, Bq0);
        iterM(t + 2, Aq2, Bq2, Aq1, Bq1);
    }
    // t = 30: no issue; drain tile 31
    {
        bf16x8 bfr[4];
        readB(Bq0, bfr);
        compute_h(Aq0, 0, bfr);
        compute_h(Aq0, 1, bfr);
        asm volatile("s_waitcnt vmcnt(0) lgkmcnt(0)" ::: "memory");
        __builtin_amdgcn_s_barrier();
    }
    // t = 31
    {
        bf16x8 bfr[4];
        readB(Bq1, bfr);
        compute_h(Aq1, 0, bfr);
        compute_h(Aq1, 1, bfr);
    }
    __syncthreads();                 // LDS free for epilogue reuse

    // ---- epilogue: per-wave LDS transpose -> full-line f32x4 stores --------
    float* tb = (float*)smem + wn * 1280;
    const int nbase = bn * BN + wn * 64;
    const int m0 = bm * BM;
    float bv[4];
#pragma unroll
    for (int nf = 0; nf < 4; ++nf) bv[nf] = bias[nbase + nf * 16 + (lane & 15)];

#pragma unroll
    for (int mf = 0; mf < 8; ++mf) {
#pragma unroll
        for (int nf = 0; nf < 4; ++nf)
#pragma unroll
            for (int j = 0; j < 4; ++j) {
                const int r = (lane >> 4) * 4 + j;
                const int c = nf * 16 + (lane & 15);
                tb[r * 80 + c] = acc[mf][nf][j] + bv[nf];
            }
        __syncthreads();
#pragma unroll
        for (int jj = 0; jj < 4; ++jj) {
            const int rr = jj * 4 + (lane >> 4);
            const int cc = (lane & 15) * 4;
            f32x4 v = *(const f32x4*)&tb[rr * 80 + cc];
            *(f32x4*)&Out[(size_t)(m0 + mf * 16 + rr) * DN + nbase + cc] = v;
        }
        __syncthreads();
    }
}

// ---- Fallback (ws too small): R13 GEMM verbatim ----------------------------
__global__ __launch_bounds__(512, 1) void corrlin_gemm_fb(
    const float* __restrict__ X, const bf16_t* __restrict__ WeffSw,
    const float* __restrict__ bias, float* __restrict__ Out)
{
    __shared__ __align__(16) char smem[81920];
    char* Ab0 = smem;
    char* Ab1 = smem + 8192;
    char* Bb0 = smem + 16384;
    char* Bb1 = smem + 49152;

    const int tid = threadIdx.x;
    const int b0  = blockIdx.x;
    const int L  = (b0 & 7) * 128 + (b0 >> 3);
    const int bm = L >> 1;
    const int bn = L & 1;
    const int m0 = bm * BM;

    const int lane = tid & 63;
    const int wn   = tid >> 6;
    const int arow = tid >> 2;
    const int aseg = tid & 3;

    f32x4 acc[8][4] = {};
    f32x4 set0[2], set1[2];

    auto issueA = [&](int kt, f32x4* s) {
        const float* p = X + (size_t)(m0 + arow) * DK + kt * BK + aseg * 8;
        s[0] = *(const f32x4*)p;
        s[1] = *(const f32x4*)(p + 4);
    };
    auto storeA = [&](const f32x4* s, char* Ab) {
        const int sw = aseg ^ ((arow >> 1) & 3);
        bf16x8 v;
#pragma unroll
        for (int j = 0; j < 4; ++j) { v[j] = (bf16_t)s[0][j]; v[4 + j] = (bf16_t)s[1][j]; }
        *(bf16x8*)(Ab + arow * 64 + (sw << 4)) = v;
    };
    auto issueB = [&](int kt, char* Bb) {
        const char* g = (const char*)WeffSw + (size_t)(bn * 32 + kt) * 32768;
#pragma unroll
        for (int c = 0; c < 4; ++c) {
            const int lin = c * 8192 + wn * 1024;
            __builtin_amdgcn_global_load_lds(
                (const __attribute__((address_space(1))) void*)(g + lin + lane * 16),
                (__attribute__((address_space(3))) void*)(Bb + lin),
                16, 0, 0);
        }
    };
    auto readB = [&](const char* Bc, bf16x8* bfr) {
        const int kb = lane >> 4;
#pragma unroll
        for (int nf = 0; nf < 4; ++nf) {
            const int row = wn * 64 + nf * 16 + (lane & 15);
            bfr[nf] = *(const bf16x8*)(Bc + row * 64 + ((kb ^ ((row >> 1) & 3)) << 4));
        }
    };
    auto compute_h = [&](const char* Ac, int h, const bf16x8* bfr) {
        bf16x8 af[4];
        const int kb = lane >> 4;
#pragma unroll
        for (int i = 0; i < 4; ++i) {
            const int row = (h * 4 + i) * 16 + (lane & 15);
            af[i] = *(const bf16x8*)(Ac + row * 64 + ((kb ^ ((row >> 1) & 3)) << 4));
        }
        __builtin_amdgcn_s_setprio(1);
#pragma unroll
        for (int i = 0; i < 4; ++i)
#pragma unroll
            for (int nf = 0; nf < 4; ++nf)
                acc[h * 4 + i][nf] = __builtin_amdgcn_mfma_f32_16x16x32_bf16(
                    af[i], bfr[nf], acc[h * 4 + i][nf], 0, 0, 0);
        __builtin_amdgcn_s_setprio(0);
    };

    auto iter = [&](int t, const char* Ac, const char* Bc, char* An, char* Bn,
                    f32x4* aStore, f32x4* aFill) {
        if (t + 1 < NKT) issueB(t + 1, Bn);
        bf16x8 bfr[4];
        readB(Bc, bfr);
        compute_h(Ac, 0, bfr);
        if (t + 1 < NKT) storeA(aStore, An);
        if (t + 2 < NKT) issueA(t + 2, aFill);
        compute_h(Ac, 1, bfr);
        if (t + 2 < NKT) {
            asm volatile("s_waitcnt vmcnt(2) lgkmcnt(0)" ::: "memory");
            __builtin_amdgcn_s_barrier();
        } else if (t + 1 < NKT) {
            asm volatile("s_waitcnt vmcnt(0) lgkmcnt(0)" ::: "memory");
            __builtin_amdgcn_s_barrier();
        }
    };

    issueA(0, set0);
    issueB(0, Bb0);
    storeA(set0, Ab0);
    issueA(1, set1);
    asm volatile("s_waitcnt vmcnt(2) lgkmcnt(0)" ::: "memory");
    __builtin_amdgcn_s_barrier();

    for (int t = 0; t < NKT; t += 2) {
        iter(t,     Ab0, Bb0, Ab1, Bb1, set1, set0);
        iter(t + 1, Ab1, Bb1, Ab0, Bb0, set0, set1);
    }
    __syncthreads();

    float* tb = (float*)smem + wn * 1280;
    const int nbase = bn * BN + wn * 64;
    float bv[4];
#pragma unroll
    for (int nf = 0; nf < 4; ++nf) bv[nf] = bias[nbase + nf * 16 + (lane & 15)];

#pragma unroll
    for (int mf = 0; mf < 8; ++mf) {
#pragma unroll
        for (int nf = 0; nf < 4; ++nf)
#pragma unroll
            for (int j = 0; j < 4; ++j) {
                const int r = (lane >> 4) * 4 + j;
                const int c = nf * 16 + (lane & 15);
                tb[r * 80 + c] = acc[mf][nf][j] + bv[nf];
            }
        __syncthreads();
#pragma unroll
        for (int jj = 0; jj < 4; ++jj) {
            const int rr = jj * 4 + (lane >> 4);
            const int cc = (lane & 15) * 4;
            f32x4 v = *(const f32x4*)&tb[rr * 80 + cc];
            *(f32x4*)&Out[(size_t)(m0 + mf * 16 + rr) * DN + nbase + cc] = v;
        }
        __syncthreads();
    }
}

extern "C" void kernel_launch(void* const* d_in, const int* in_sizes, int n_in,
                              void* d_out, int out_size, void* d_ws, size_t ws_size,
                              hipStream_t stream) {
    const float* x  = (const float*)d_in[0];
    const float* W  = (const float*)d_in[1];
    const float* b  = (const float*)d_in[2];
    const float* Vr = (const float*)d_in[3];
    const float* C  = (const float*)d_in[4];
    float* out = (float*)d_out;

    const int M = in_sizes[0] / DK;            // 65536
    bf16_t* WeffSw = (bf16_t*)d_ws;            // 2 MB pre-swizzled W_eff
    bf16_t* Xsw = (bf16_t*)((char*)d_ws + (2u << 20));  // 128 MB pre-swizzled x

    const size_t need = (2u << 20) + (size_t)M * DK * sizeof(bf16_t);

    weff_kernel<<<DN, 128, 0, stream>>>(W, Vr, C, WeffSw);

    const int mtiles = M / BM;                 // 512
    const int nwg = mtiles * (DN / BN);        // 1024

    if (ws_size >= need) {
        xconv_kernel<<<(M * (DK / 8)) / 256, 256, 0, stream>>>(x, Xsw);
        corrlin_gemm_dma<<<nwg, 512, 0, stream>>>(Xsw, WeffSw, b, out);
    } else {
        corrlin_gemm_fb<<<nwg, 512, 0, stream>>>(x, WeffSw, b, out);
    }
}

// Round 17
// 208.579 us; speedup vs baseline: 7.5759x; 1.2641x over previous
//
#include <hip/hip_runtime.h>
#include <hip/hip_bf16.h>

typedef __bf16 bf16_t;
typedef __bf16 bf16x8 __attribute__((ext_vector_type(8)));
typedef float  f32x4  __attribute__((ext_vector_type(4)));

#define DK 1024   // d_in  (K)
#define DN 1024   // d_out (N)
#define RNK 32
#define BM 128
#define BN 512
#define BK 32
#define NKT 32

// ---- Pass 1: W_eff = W + C @ V_r^T, bf16, PRE-SWIZZLED (R7 layout) ---------
__global__ void weff_kernel(const float* __restrict__ W,
                            const float* __restrict__ Vr,
                            const float* __restrict__ C,
                            bf16_t* __restrict__ WeffSw)
{
    const int o  = blockIdx.x;
    const int g  = threadIdx.x;
    const int d0 = g * 8;

    f32x4 cv[8];
#pragma unroll
    for (int q = 0; q < 8; ++q) cv[q] = *(const f32x4*)(C + o * RNK + q * 4);

    const f32x4* wrow = (const f32x4*)(W + (size_t)o * DK + d0);
    f32x4 w0 = wrow[0], w1 = wrow[1];
    float acc[8];
#pragma unroll
    for (int e = 0; e < 4; ++e) { acc[e] = w0[e]; acc[4 + e] = w1[e]; }

#pragma unroll
    for (int e = 0; e < 8; ++e) {
        const f32x4* vre = (const f32x4*)(Vr + (size_t)(d0 + e) * RNK);
        float s = 0.f;
#pragma unroll
        for (int q = 0; q < 8; ++q) {
            f32x4 v = vre[q];
            s += cv[q][0] * v[0] + cv[q][1] * v[1] + cv[q][2] * v[2] + cv[q][3] * v[3];
        }
        acc[e] += s;
    }

    bf16x8 out;
#pragma unroll
    for (int e = 0; e < 8; ++e) out[e] = (bf16_t)acc[e];

    const int bn = o >> 9, rloc = o & 511;
    const int kt = d0 >> 5, seg = (d0 >> 3) & 3;
    const int sw = seg ^ ((rloc >> 1) & 3);
    const size_t byte = (size_t)(bn * 32 + kt) * 32768 + rloc * 64 + (sw << 4);
    *(bf16x8*)((char*)WeffSw + byte) = out;
}

// ---- Pass 2: all-DMA GEMM, A = fp32 DIRECT from x (per-lane swizzled src) --
// A-tile in LDS: 128 rows x 32 k fp32 (16KB), 16B-granule swizzle
// gir = half ^ (row&7) where half = k>>2. DMA source per lane computes the
// inverse swizzle on the row-major x -- no conversion pass, no reg staging.
// Fragments: 2x ds_read_b128 fp32 + in-reg cvt to bf16x8.
// B unchanged (bf16, pre-swizzled Weff, probe-validated).
// Uniform depth-2: issue tile t+2 (4 B + 2 A = 6 ops), vmcnt(6) drains t+1.
__global__ __launch_bounds__(512, 1) void corrlin_gemm_dma(
    const float* __restrict__ X, const bf16_t* __restrict__ WeffSw,
    const float* __restrict__ bias, float* __restrict__ Out)
{
    __shared__ __align__(16) char smem[147456];
    char* Aq0 = smem;                 // 16KB each (fp32 A tiles)
    char* Aq1 = smem + 16384;
    char* Aq2 = smem + 32768;
    char* Bq0 = smem + 49152;         // 32KB each (bf16 B tiles)
    char* Bq1 = smem + 81920;
    char* Bq2 = smem + 114688;

    const int tid = threadIdx.x;
    const int b0  = blockIdx.x;
    const int L  = (b0 & 7) * 128 + (b0 >> 3);   // XCD-bijective, nwg=1024
    const int bm = L >> 1;
    const int bn = L & 1;
    const int m0 = bm * BM;

    const int lane = tid & 63;
    const int wn   = tid >> 6;

    f32x4 acc[8][4] = {};

    // A DMA: 16KB tile / 8 waves = 2KB/wave = 2 ops of 1KB. Lane's 16B granule
    // g16 = wn*128 + c*64 + lane; row = g16>>3; gir = g16&7; source half =
    // gir ^ (row&7); src = x[m0+row][kt*32 + half*4 ..+4] (16B fp32).
    auto issueA = [&](int kt, char* Ab) {
#pragma unroll
        for (int c = 0; c < 2; ++c) {
            const int g16 = wn * 128 + c * 64 + lane;
            const int row = g16 >> 3;
            const int half = (g16 & 7) ^ (row & 7);
            const float* src = X + (size_t)(m0 + row) * DK + kt * 32 + half * 4;
            __builtin_amdgcn_global_load_lds(
                (const __attribute__((address_space(1))) void*)src,
                (__attribute__((address_space(3))) void*)(Ab + wn * 2048 + c * 1024),
                16, 0, 0);
        }
    };
    auto issueB = [&](int kt, char* Bb) {
        const char* g = (const char*)WeffSw + (size_t)(bn * 32 + kt) * 32768;
#pragma unroll
        for (int c = 0; c < 4; ++c) {
            const int lin = c * 8192 + wn * 1024;
            __builtin_amdgcn_global_load_lds(
                (const __attribute__((address_space(1))) void*)(g + lin + lane * 16),
                (__attribute__((address_space(3))) void*)(Bb + lin),
                16, 0, 0);
        }
    };
    auto readB = [&](const char* Bc, bf16x8* bfr) {
        const int kb = lane >> 4;
#pragma unroll
        for (int nf = 0; nf < 4; ++nf) {
            const int row = wn * 64 + nf * 16 + (lane & 15);
            bfr[nf] = *(const bf16x8*)(Bc + row * 64 + ((kb ^ ((row >> 1) & 3)) << 4));
        }
    };
    auto compute_h = [&](const char* Ac, int h, const bf16x8* bfr) {
        bf16x8 af[4];
        const int kb = lane >> 4;
#pragma unroll
        for (int i = 0; i < 4; ++i) {
            const int row = (h * 4 + i) * 16 + (lane & 15);
            const int rs = row & 7;
            f32x4 v0 = *(const f32x4*)(Ac + row * 128 + (((kb * 2)     ^ rs) << 4));
            f32x4 v1 = *(const f32x4*)(Ac + row * 128 + (((kb * 2 + 1) ^ rs) << 4));
#pragma unroll
            for (int j = 0; j < 4; ++j) { af[i][j] = (bf16_t)v0[j]; af[i][4 + j] = (bf16_t)v1[j]; }
        }
        __builtin_amdgcn_s_setprio(1);
#pragma unroll
        for (int i = 0; i < 4; ++i)
#pragma unroll
            for (int nf = 0; nf < 4; ++nf)
                acc[h * 4 + i][nf] = __builtin_amdgcn_mfma_f32_16x16x32_bf16(
                    af[i], bfr[nf], acc[h * 4 + i][nf], 0, 0, 0);
        __builtin_amdgcn_s_setprio(0);
    };

    // steady-state iteration (t+2 <= 31 guaranteed by caller)
    auto iterM = [&](int t, const char* Ac, const char* Bc, char* An2, char* Bn2) {
        issueB(t + 2, Bn2);               // 4 ops
        issueA(t + 2, An2);               // 2 ops
        bf16x8 bfr[4];
        readB(Bc, bfr);
        compute_h(Ac, 0, bfr);
        compute_h(Ac, 1, bfr);
        asm volatile("s_waitcnt vmcnt(6) lgkmcnt(0)" ::: "memory");  // drain tile t+1
        __builtin_amdgcn_s_barrier();
    };

    // ---- prologue: tiles 0,1 issued; tile 0 landed -------------------------
    issueB(0, Bq0); issueA(0, Aq0);
    issueB(1, Bq1); issueA(1, Aq1);
    asm volatile("s_waitcnt vmcnt(6)" ::: "memory");    // tile 0 complete
    __builtin_amdgcn_s_barrier();

    // main: t = 0..29, 3-cyclic buffers, guard-free
    for (int t = 0; t < 30; t += 3) {
        iterM(t,     Aq0, Bq0, Aq2, Bq2);
        iterM(t + 1, Aq1, Bq1, Aq0, Bq0);
        iterM(t + 2, Aq2, Bq2, Aq1, Bq1);
    }
    // t = 30: no issue; drain tile 31
    {
        bf16x8 bfr[4];
        readB(Bq0, bfr);
        compute_h(Aq0, 0, bfr);
        compute_h(Aq0, 1, bfr);
        asm volatile("s_waitcnt vmcnt(0) lgkmcnt(0)" ::: "memory");
        __builtin_amdgcn_s_barrier();
    }
    // t = 31
    {
        bf16x8 bfr[4];
        readB(Bq1, bfr);
        compute_h(Aq1, 0, bfr);
        compute_h(Aq1, 1, bfr);
    }
    __syncthreads();                 // LDS free for epilogue reuse

    // ---- epilogue: per-wave LDS transpose -> full-line f32x4 stores --------
    float* tb = (float*)smem + wn * 1280;
    const int nbase = bn * BN + wn * 64;
    float bv[4];
#pragma unroll
    for (int nf = 0; nf < 4; ++nf) bv[nf] = bias[nbase + nf * 16 + (lane & 15)];

#pragma unroll
    for (int mf = 0; mf < 8; ++mf) {
#pragma unroll
        for (int nf = 0; nf < 4; ++nf)
#pragma unroll
            for (int j = 0; j < 4; ++j) {
                const int r = (lane >> 4) * 4 + j;
                const int c = nf * 16 + (lane & 15);
                tb[r * 80 + c] = acc[mf][nf][j] + bv[nf];
            }
        __syncthreads();
#pragma unroll
        for (int jj = 0; jj < 4; ++jj) {
            const int rr = jj * 4 + (lane >> 4);
            const int cc = (lane & 15) * 4;
            f32x4 v = *(const f32x4*)&tb[rr * 80 + cc];
            *(f32x4*)&Out[(size_t)(m0 + mf * 16 + rr) * DN + nbase + cc] = v;
        }
        __syncthreads();
    }
}

extern "C" void kernel_launch(void* const* d_in, const int* in_sizes, int n_in,
                              void* d_out, int out_size, void* d_ws, size_t ws_size,
                              hipStream_t stream) {
    const float* x  = (const float*)d_in[0];
    const float* W  = (const float*)d_in[1];
    const float* b  = (const float*)d_in[2];
    const float* Vr = (const float*)d_in[3];
    const float* C  = (const float*)d_in[4];
    float* out = (float*)d_out;

    const int M = in_sizes[0] / DK;            // 65536
    bf16_t* WeffSw = (bf16_t*)d_ws;            // 2 MB pre-swizzled W_eff

    weff_kernel<<<DN, 128, 0, stream>>>(W, Vr, C, WeffSw);

    const int mtiles = M / BM;                 // 512
    const int nwg = mtiles * (DN / BN);        // 1024
    corrlin_gemm_dma<<<nwg, 512, 0, stream>>>(x, WeffSw, b, out);
}